// Round 30
// baseline (121.035 us; speedup 1.0000x reference)
//
#include <hip/hip_runtime.h>
#include <stdint.h>

typedef unsigned short u16;
typedef __attribute__((ext_vector_type(8))) short bf16x8;
typedef __attribute__((ext_vector_type(4))) float f32x4;
typedef __attribute__((ext_vector_type(4))) unsigned short u16x4;
typedef __attribute__((ext_vector_type(4))) uint32_t u32x4;

__device__ __forceinline__ u16 f2bf(float f) {
  union { float f; uint32_t u; } c; c.f = f;
  uint32_t u = c.u;
  return (u16)((u + 0x7fffu + ((u >> 16) & 1u)) >> 16);
}

__device__ __forceinline__ uint32_t pk_bf16(float lo, float hi) {
  uint32_t d;
  asm("v_cvt_pk_bf16_f32 %0, %1, %2" : "=v"(d) : "v"(lo), "v"(hi));
  return d;
}

__device__ __forceinline__ void gload_lds16(const u16* g, u16* l) {
  __builtin_amdgcn_global_load_lds(
      (const __attribute__((address_space(1))) void*)g,
      (__attribute__((address_space(3))) void*)l, 16, 0, 0);
}

// cast W only (x is consumed as fp32 directly by gemm_qkv)
__global__ void cast_w(const float* __restrict__ Wq, const float* __restrict__ Wk,
                       const float* __restrict__ Wv, const float* __restrict__ Wo,
                       u16* __restrict__ Wcat, u16* __restrict__ Wob) {
  int i = (blockIdx.x * blockDim.x + threadIdx.x) * 4;
  const int stride = gridDim.x * blockDim.x * 4;
  for (; i < 4194304; i += stride) {
    const int sel = i >> 20, off = i & 1048575;
    const float* src = ((sel == 0) ? Wq : (sel == 1) ? Wk : (sel == 2) ? Wv : Wo) + off;
    u16* dst = (sel < 3) ? (Wcat + i) : (Wob + off);
    float4 v = *reinterpret_cast<const float4*>(src);
    u16x4 o = { f2bf(v.x), f2bf(v.y), f2bf(v.z), f2bf(v.w) };
    *reinterpret_cast<u16x4*>(dst) = o;
  }
}

#define QSCALE 0.18033688011112042f  /* 1/sqrt(64) * log2(e) */

// QKV projection: C = x(FP32) @ Wcat(bf16)^T.  128x128 tile, BK=32, 512
// threads = 8 waves (4M x 2N).  A staged DIRECTLY from fp32 x via
// global_load_lds (BK=32 fp32 = 128B rows, slot^(row&7) swizzle); fragments
// converted in-register with v_cvt_pk_bf16_f32 (RNE — bit-identical to the
// old cast kernel).  B staged bf16 as R26.  LDS 48KB -> 3 blocks/CU.
// Epilogue: scatter Q(pre-scaled)/K/Vt.
__global__ __launch_bounds__(512) void gemm_qkv(
    const float* __restrict__ A, const u16* __restrict__ B,
    u16* __restrict__ o0, u16* __restrict__ o1, u16* __restrict__ o2)
{
  const int K = 1024;
  __shared__ __align__(16) float Af[2][128 * 32];
  __shared__ __align__(16) u16 Bs[2][128 * 32];
  const int tid = threadIdx.x;
  const int w = tid >> 6, l = tid & 63;
  const int m0 = blockIdx.y * 128, n0 = blockIdx.x * 128;
  const int wm = w >> 1, wn = w & 1;
  const int lr = l & 15, hi = l >> 4;
  f32x4 acc[2][4] = {};

  // A staging: 1024 16B-chunks (8/row of 128B); chunks c0=tid, c1=tid+512.
  const int ra0 = tid >> 3, sl0 = tid & 7;
  const int ra1 = ra0 + 64;
  const float* Apf0 = A + (size_t)(m0 + ra0) * K + ((sl0 ^ (ra0 & 7)) << 2);
  const float* Apf1 = A + (size_t)(m0 + ra1) * K + ((sl0 ^ (ra1 & 7)) << 2);
  // B staging: 512 16B-chunks (4/row of 64B), as R26.
  const int rb = tid >> 2, sb = (tid & 3) ^ ((rb >> 1) & 3);
  const u16* Bp = B + (size_t)(n0 + rb) * K + sb * 8;

  gload_lds16((const u16*)Apf0, (u16*)&Af[0][0] + tid * 8);
  gload_lds16((const u16*)Apf1, (u16*)&Af[0][0] + (tid + 512) * 8);
  gload_lds16(Bp, &Bs[0][tid * 8]);

  // fragment read byte offsets
  int aoff[2][2], boff[4];
#pragma unroll
  for (int m = 0; m < 2; ++m) {
    const int row = wm * 32 + m * 16 + lr;
#pragma unroll
    for (int jj = 0; jj < 2; ++jj)
      aoff[m][jj] = (row << 7) + (((2 * hi + jj) ^ (row & 7)) << 4);
  }
#pragma unroll
  for (int n = 0; n < 4; ++n) {
    const int row = wn * 64 + n * 16 + lr;
    boff[n] = row * 64 + ((hi ^ ((row >> 1) & 3)) << 4);
  }

  int buf = 0;
  for (int k0 = 0; k0 < K; k0 += 32) {
    if (k0 + 32 < K) {
      const int nb = buf ^ 1;
      gload_lds16((const u16*)(Apf0 + k0 + 32), (u16*)&Af[nb][0] + tid * 8);
      gload_lds16((const u16*)(Apf1 + k0 + 32), (u16*)&Af[nb][0] + (tid + 512) * 8);
      gload_lds16(Bp + k0 + 32, &Bs[nb][tid * 8]);
      asm volatile("s_waitcnt vmcnt(3)" ::: "memory");
    } else {
      asm volatile("s_waitcnt vmcnt(0)" ::: "memory");
    }
    __builtin_amdgcn_sched_barrier(0);
    __builtin_amdgcn_s_barrier();
    bf16x8 af[2], bfr[4];
#pragma unroll
    for (int m = 0; m < 2; ++m) {
      f32x4 a0 = *(const f32x4*)((const char*)&Af[buf][0] + aoff[m][0]);
      f32x4 a1 = *(const f32x4*)((const char*)&Af[buf][0] + aoff[m][1]);
      union { u32x4 u; bf16x8 v; } cc;
      cc.u = (u32x4){ pk_bf16(a0[0], a0[1]), pk_bf16(a0[2], a0[3]),
                      pk_bf16(a1[0], a1[1]), pk_bf16(a1[2], a1[3]) };
      af[m] = cc.v;
    }
#pragma unroll
    for (int n = 0; n < 4; ++n)
      bfr[n] = *(const bf16x8*)((const char*)&Bs[buf][0] + boff[n]);
    __builtin_amdgcn_s_setprio(1);
#pragma unroll
    for (int m = 0; m < 2; ++m)
#pragma unroll
      for (int n = 0; n < 4; ++n)
        acc[m][n] = __builtin_amdgcn_mfma_f32_16x16x32_bf16(af[m], bfr[n], acc[m][n], 0, 0, 0);
    __builtin_amdgcn_s_setprio(0);
    __builtin_amdgcn_s_barrier();
    buf ^= 1;
  }

#pragma unroll
  for (int mm = 0; mm < 2; ++mm) {
#pragma unroll
    for (int nn = 0; nn < 4; ++nn) {
      const int ng = n0 + wn * 64 + nn * 16 + lr;
      const int mat = ng >> 10;
      const int col = ng & 1023;
      const int h = col >> 6, dh = col & 63;
#pragma unroll
      for (int r = 0; r < 4; ++r) {
        const int mg = m0 + wm * 32 + mm * 16 + (hi << 2) + r;
        const int b = mg >> 11, s = mg & 2047;
        if (mat == 0)
          o0[(((size_t)(b * 16 + h)) * 2048 + s) * 64 + dh] = f2bf(acc[mm][nn][r] * QSCALE);
        else if (mat == 1)
          o1[(((size_t)(b * 16 + h)) * 2048 + s) * 64 + dh] = f2bf(acc[mm][nn][r]);
        else
          o2[(((size_t)(b * 16 + h)) * 64 + dh) * 2048 + s] = f2bf(acc[mm][nn][r]);
      }
    }
  }
}

// out-projection: C = ctx(bf16) @ Wo(bf16)^T + bias, fp32 out (R26 config).
__global__ __launch_bounds__(512) void gemm_out(
    const u16* __restrict__ A, const u16* __restrict__ B,
    int M, int N, int K,
    float* __restrict__ fo, const float* __restrict__ bias)
{
  __shared__ __align__(16) u16 As[2][128 * 32];
  __shared__ __align__(16) u16 Bs[2][128 * 32];
  const int tid = threadIdx.x;
  const int w = tid >> 6, l = tid & 63;
  const int m0 = blockIdx.y * 128, n0 = blockIdx.x * 128;
  const int wm = w >> 1, wn = w & 1;
  const int lr = l & 15, hi = l >> 4;
  f32x4 acc[2][4] = {};

  const int ra = tid >> 2, sa = (tid & 3) ^ ((ra >> 1) & 3);
  const u16* Ap = A + (size_t)(m0 + ra) * K + sa * 8;
  const u16* Bp = B + (size_t)(n0 + ra) * K + sa * 8;

  gload_lds16(Ap, &As[0][tid * 8]);
  gload_lds16(Bp, &Bs[0][tid * 8]);

  int aoff[2], boff[4];
#pragma unroll
  for (int m = 0; m < 2; ++m) {
    const int row = wm * 32 + m * 16 + lr;
    aoff[m] = row * 64 + ((hi ^ ((row >> 1) & 3)) << 4);
  }
#pragma unroll
  for (int n = 0; n < 4; ++n) {
    const int row = wn * 64 + n * 16 + lr;
    boff[n] = row * 64 + ((hi ^ ((row >> 1) & 3)) << 4);
  }

  int buf = 0;
  for (int k0 = 0; k0 < K; k0 += 32) {
    if (k0 + 32 < K) {
      const int nb = buf ^ 1;
      gload_lds16(Ap + k0 + 32, &As[nb][tid * 8]);
      gload_lds16(Bp + k0 + 32, &Bs[nb][tid * 8]);
      asm volatile("s_waitcnt vmcnt(2)" ::: "memory");
    } else {
      asm volatile("s_waitcnt vmcnt(0)" ::: "memory");
    }
    __builtin_amdgcn_sched_barrier(0);
    __builtin_amdgcn_s_barrier();
    bf16x8 af[2], bfr[4];
#pragma unroll
    for (int m = 0; m < 2; ++m)
      af[m] = *(const bf16x8*)((const char*)&As[buf][0] + aoff[m]);
#pragma unroll
    for (int n = 0; n < 4; ++n)
      bfr[n] = *(const bf16x8*)((const char*)&Bs[buf][0] + boff[n]);
    __builtin_amdgcn_s_setprio(1);
#pragma unroll
    for (int m = 0; m < 2; ++m)
#pragma unroll
      for (int n = 0; n < 4; ++n)
        acc[m][n] = __builtin_amdgcn_mfma_f32_16x16x32_bf16(af[m], bfr[n], acc[m][n], 0, 0, 0);
    __builtin_amdgcn_s_setprio(0);
    __builtin_amdgcn_s_barrier();
    buf ^= 1;
  }

#pragma unroll
  for (int mm = 0; mm < 2; ++mm) {
#pragma unroll
    for (int nn = 0; nn < 4; ++nn) {
      const int ng = n0 + wn * 64 + nn * 16 + lr;
      const float bv = bias[ng];
#pragma unroll
      for (int r = 0; r < 4; ++r) {
        const int mg = m0 + wm * 32 + mm * 16 + (hi << 2) + r;
        fo[(size_t)mg * N + ng] = acc[mm][nn][r] + bv;
      }
    }
  }
}

// Flash attention, causal.  UNIFORM-WORK pairing + XCD clustering.
// Row-sums on the MFMA pipe; lane-local epilogue normalizer.
__global__ __launch_bounds__(256) void flash_attn(
    const u16* __restrict__ Qg, const u16* __restrict__ Kg,
    const u16* __restrict__ Vtg, u16* __restrict__ ctx)
{
  __shared__ __align__(16) u16 Ks[2][4096];
  __shared__ __align__(16) u16 Vts[2][4096];
  __shared__ __align__(16) u16 PT[4][1024];
  const int tid = threadIdx.x, w = tid >> 6, l = tid & 63;
  const int lr = l & 15, hi = l >> 4;
  const int bid = blockIdx.x;
  const int xcd = bid & 7, j = bid >> 3;
  const int bh = xcd + ((j & 3) << 3);
  const int p = j >> 2;              // pair index [0,16)
  const size_t kqbase = (size_t)bh * (2048 * 64);
  const int h = bh & 15, b = bh >> 4;

  bf16x8 onesf;
#pragma unroll
  for (int i = 0; i < 8; ++i) onesf[i] = (short)0x3F80;

  const int c0 = w * 128 + l;
  const int c1 = c0 + 64;
  const int r0 = c0 >> 3, p0 = c0 & 7;
  const int r1 = c1 >> 3, p1 = c1 & 7;
  const u16* kg0 = Kg + kqbase + r0 * 64 + p0 * 8;
  const u16* kg1 = Kg + kqbase + r1 * 64 + p1 * 8;
  const u16* vg0 = Vtg + kqbase + (size_t)r0 * 2048 + p0 * 8;
  const u16* vg1 = Vtg + kqbase + (size_t)r1 * 2048 + p1 * 8;
  const int kw0 = (r0 << 7) + ((p0 ^ (r0 & 7)) << 4);
  const int kw1 = (r1 << 7) + ((p1 ^ (r1 & 7)) << 4);

  for (int seg = 0; seg < 2; ++seg) {
    const int qt = seg ? (31 - p) : p;
    const int q0 = qt * 64;
    const int nkt = qt + 1;
    const int qg = q0 + w * 16 + lr;

    if (seg) __builtin_amdgcn_s_barrier();

    bf16x8 qf[2];
    {
      const u16* qp = Qg + kqbase + (size_t)(q0 + w * 16 + lr) * 64 + hi * 8;
      qf[0] = *(const bf16x8*)(qp);
      qf[1] = *(const bf16x8*)(qp + 32);
    }

    f32x4 acc[4] = {};
    f32x4 acc_ls = {};

    bf16x8 sk0 = *(const bf16x8*)kg0;
    bf16x8 sk1 = *(const bf16x8*)kg1;
    bf16x8 sv0 = *(const bf16x8*)vg0;
    bf16x8 sv1 = *(const bf16x8*)vg1;
    *(bf16x8*)((char*)&Ks[0][0] + kw0) = sk0;
    *(bf16x8*)((char*)&Ks[0][0] + kw1) = sk1;
    *(bf16x8*)((char*)&Vts[0][0] + kw0) = sv0;
    *(bf16x8*)((char*)&Vts[0][0] + kw1) = sv1;
    if (nkt > 1) {
      sk0 = *(const bf16x8*)(kg0 + 4096);
      sk1 = *(const bf16x8*)(kg1 + 4096);
      sv0 = *(const bf16x8*)(vg0 + 64);
      sv1 = *(const bf16x8*)(vg1 + 64);
    }
    asm volatile("s_waitcnt lgkmcnt(0)" ::: "memory");
    __builtin_amdgcn_sched_barrier(0);
    __builtin_amdgcn_s_barrier();

    int buf = 0;
    for (int kt = 0; kt < nkt; ++kt) {
      {
        const u16* ksb = &Ks[buf][0];
        const u16* vsb = &Vts[buf][0];
        f32x4 sv[4];
        __builtin_amdgcn_s_setprio(1);
#pragma unroll
        for (int cf = 0; cf < 4; ++cf) {
          f32x4 z = {};
#pragma unroll
          for (int ch = 0; ch < 2; ++ch) {
            const int krow = cf * 16 + lr;
            const int boff = ((krow << 7) + ((ch * 32 + hi * 8) << 1)) ^ ((krow & 7) << 4);
            bf16x8 kf = *(const bf16x8*)((const char*)ksb + boff);
            z = __builtin_amdgcn_mfma_f32_16x16x32_bf16(kf, qf[ch], z, 0, 0, 0);
          }
          sv[cf] = z;
        }
        __builtin_amdgcn_s_setprio(0);

        const bool diag = (kt == nkt - 1);
        const int kb = kt * 64 + hi * 4;
#pragma unroll
        for (int cf = 0; cf < 4; ++cf) {
          f32x4 pv;
#pragma unroll
          for (int r = 0; r < 4; ++r) {
            float s = sv[cf][r];
            if (diag && (kb + cf * 16 + r) > qg) s = -1e30f;
            pv[r] = exp2f(s);
          }
          sv[cf] = pv;
        }

        {
          const int rowb = lr << 7;
          const int swz = (lr & 7) << 4;
#pragma unroll
          for (int cf = 0; cf < 4; ++cf) {
            uint32_t d0 = pk_bf16(sv[cf][0], sv[cf][1]);
            uint32_t d1 = pk_bf16(sv[cf][2], sv[cf][3]);
            uint2 val = { d0, d1 };
            const int boff = (rowb + ((cf * 16 + hi * 4) << 1)) ^ swz;
            *(uint2*)((char*)&PT[w][0] + boff) = val;
          }
        }

#pragma unroll
        for (int ch = 0; ch < 2; ++ch) {
          const int boffp = ((lr << 7) + (ch * 64 + hi * 16)) ^ ((lr & 7) << 4);
          bf16x8 pa = *(const bf16x8*)((const char*)&PT[w][0] + boffp);
          __builtin_amdgcn_s_setprio(1);
          acc_ls = __builtin_amdgcn_mfma_f32_16x16x32_bf16(pa, onesf, acc_ls, 0, 0, 0);
#pragma unroll
          for (int df = 0; df < 4; ++df) {
            const int vrow = df * 16 + lr;
            const int boffv = ((vrow << 7) + ((ch * 32 + hi * 8) << 1)) ^ ((vrow & 7) << 4);
            bf16x8 vf = *(const bf16x8*)((const char*)vsb + boffv);
            acc[df] = __builtin_amdgcn_mfma_f32_16x16x32_bf16(pa, vf, acc[df], 0, 0, 0);
          }
          __builtin_amdgcn_s_setprio(0);
        }
      }
      if (kt + 1 < nkt) {
        char* kb_ = (char*)&Ks[buf ^ 1][0];
        char* vb_ = (char*)&Vts[buf ^ 1][0];
        *(bf16x8*)(kb_ + kw0) = sk0;
        *(bf16x8*)(kb_ + kw1) = sk1;
        *(bf16x8*)(vb_ + kw0) = sv0;
        *(bf16x8*)(vb_ + kw1) = sv1;
        if (kt + 2 < nkt) {
          sk0 = *(const bf16x8*)(kg0 + (size_t)(kt + 2) * 4096);
          sk1 = *(const bf16x8*)(kg1 + (size_t)(kt + 2) * 4096);
          sv0 = *(const bf16x8*)(vg0 + (kt + 2) * 64);
          sv1 = *(const bf16x8*)(vg1 + (kt + 2) * 64);
        }
        asm volatile("s_waitcnt lgkmcnt(0)" ::: "memory");
        __builtin_amdgcn_sched_barrier(0);
        __builtin_amdgcn_s_barrier();
      }
      buf ^= 1;
    }

#pragma unroll
    for (int r = 0; r < 4; ++r) {
      const float inv = 1.0f / acc_ls[r];
      const int s = q0 + w * 16 + hi * 4 + r;
      const size_t rowbase = ((size_t)(b * 2048 + s)) * 1024 + h * 64;
#pragma unroll
      for (int df = 0; df < 4; ++df)
        ctx[rowbase + df * 16 + lr] = f2bf(acc[df][r] * inv);
    }
  }
}

extern "C" void kernel_launch(void* const* d_in, const int* in_sizes, int n_in,
                              void* d_out, int out_size, void* d_ws, size_t ws_size,
                              hipStream_t stream) {
  const float* x  = (const float*)d_in[0];
  const float* Wq = (const float*)d_in[1];
  const float* Wk = (const float*)d_in[2];
  const float* Wv = (const float*)d_in[3];
  const float* Wo = (const float*)d_in[4];
  const float* bo = (const float*)d_in[5];
  float* out = (float*)d_out;

  const size_t MB = 1ull << 20;
  if (ws_size < 48 * MB) return;  // loud failure instead of corruption
  char* ws = (char*)d_ws;
  u16* Wcat = (u16*)(ws + 8 * MB);    // [3072][1024]  (Wq|Wk|Wv)
  u16* Wob  = (u16*)(ws + 14 * MB);   // [1024][1024]
  u16* Qb   = (u16*)(ws + 16 * MB);   // [B,H,S,DH]  (pre-scaled)
  u16* Kb   = (u16*)(ws + 24 * MB);   // [B,H,S,DH]
  u16* Vtb  = (u16*)(ws + 32 * MB);   // [B,H,DH,S]
  u16* ctxb = (u16*)(ws + 40 * MB);   // [4096][1024]

  hipLaunchKernelGGL(cast_w, dim3(2048), dim3(256), 0, stream,
                     Wq, Wk, Wv, Wo, Wcat, Wob);
  hipLaunchKernelGGL(gemm_qkv, dim3(24, 32), dim3(512), 0, stream,
                     x, Wcat, Qb, Kb, Vtb);
  hipLaunchKernelGGL(flash_attn, dim3(512), dim3(256), 0, stream, Qb, Kb, Vtb, ctxb);
  hipLaunchKernelGGL(gemm_out, dim3(8, 32), dim3(512), 0, stream,
                     ctxb, Wob, 4096, 1024, 1024, out, bo);
}

// Round 31
// 117.454 us; speedup vs baseline: 1.0305x; 1.0305x over previous
//
#include <hip/hip_runtime.h>
#include <stdint.h>

typedef unsigned short u16;
typedef __attribute__((ext_vector_type(8))) short bf16x8;
typedef __attribute__((ext_vector_type(4))) float f32x4;
typedef __attribute__((ext_vector_type(4))) unsigned short u16x4;

__device__ __forceinline__ u16 f2bf(float f) {
  union { float f; uint32_t u; } c; c.f = f;
  uint32_t u = c.u;
  return (u16)((u + 0x7fffu + ((u >> 16) & 1u)) >> 16);
}

__device__ __forceinline__ uint32_t pk_bf16(float lo, float hi) {
  uint32_t d;
  asm("v_cvt_pk_bf16_f32 %0, %1, %2" : "=v"(d) : "v"(lo), "v"(hi));
  return d;
}

__device__ __forceinline__ void gload_lds16(const u16* g, u16* l) {
  __builtin_amdgcn_global_load_lds(
      (const __attribute__((address_space(1))) void*)g,
      (__attribute__((address_space(3))) void*)l, 16, 0, 0);
}

// one launch: x -> xb, Wq|Wk|Wv -> Wcat, Wo -> Wob
__global__ void cast_all(const float* __restrict__ x,
                         const float* __restrict__ Wq, const float* __restrict__ Wk,
                         const float* __restrict__ Wv, const float* __restrict__ Wo,
                         u16* __restrict__ xb, u16* __restrict__ Wcat, u16* __restrict__ Wob) {
  int i = (blockIdx.x * blockDim.x + threadIdx.x) * 4;
  const int stride = gridDim.x * blockDim.x * 4;
  for (; i < 8388608; i += stride) {
    const float* src;
    u16* dst;
    if (i < 4194304) {
      src = x + i; dst = xb + i;
    } else {
      const int j = i - 4194304;
      const int sel = j >> 20, off = j & 1048575;
      src = ((sel == 0) ? Wq : (sel == 1) ? Wk : (sel == 2) ? Wv : Wo) + off;
      dst = (sel < 3) ? (Wcat + j) : (Wob + off);
    }
    float4 v = *reinterpret_cast<const float4*>(src);
    u16x4 o = { f2bf(v.x), f2bf(v.y), f2bf(v.z), f2bf(v.w) };
    *reinterpret_cast<u16x4*>(dst) = o;
  }
}

#define QSCALE 0.18033688011112042f  /* 1/sqrt(64) * log2(e) */

// C = A @ B^T.  128x128 tile, BK=32, 512 threads = 8 waves (4M x 2N, each
// wave 32x64 = 2x4 frags).  global_load_lds staging (1 A + 1 B chunk per
// thread, counted vmcnt(2)); slot-swizzle.  R26/R29-measured best: 45.9 us.
// EPI 0: scatter Q(pre-scaled)/K/Vt.  EPI 1: fp32 out + bias.
template<int EPI>
__global__ __launch_bounds__(512) void gemm_bt(
    const u16* __restrict__ A, const u16* __restrict__ B,
    int M, int N, int K,
    u16* __restrict__ o0, u16* __restrict__ o1, u16* __restrict__ o2,
    float* __restrict__ fo, const float* __restrict__ bias)
{
  __shared__ __align__(16) u16 As[2][128 * 32];
  __shared__ __align__(16) u16 Bs[2][128 * 32];
  const int tid = threadIdx.x;
  const int w = tid >> 6, l = tid & 63;
  const int m0 = blockIdx.y * 128, n0 = blockIdx.x * 128;
  const int wm = w >> 1, wn = w & 1;
  const int lr = l & 15, hi = l >> 4;
  f32x4 acc[2][4] = {};

  // staging: chunk idx = tid (512 16B-chunks per 128x32 tile); 1 A + 1 B.
  const int ra = tid >> 2, sa = (tid & 3) ^ ((ra >> 1) & 3);
  const u16* Ap = A + (size_t)(m0 + ra) * K + sa * 8;
  const u16* Bp = B + (size_t)(n0 + ra) * K + sa * 8;

  gload_lds16(Ap, &As[0][tid * 8]);
  gload_lds16(Bp, &Bs[0][tid * 8]);

  // fragment read byte offsets (swizzled to match the staged layout)
  int aoff[2], boff[4];
#pragma unroll
  for (int m = 0; m < 2; ++m) {
    const int row = wm * 32 + m * 16 + lr;
    aoff[m] = row * 64 + ((hi ^ ((row >> 1) & 3)) << 4);
  }
#pragma unroll
  for (int n = 0; n < 4; ++n) {
    const int row = wn * 64 + n * 16 + lr;
    boff[n] = row * 64 + ((hi ^ ((row >> 1) & 3)) << 4);
  }

  int buf = 0;
  for (int k0 = 0; k0 < K; k0 += 32) {
    if (k0 + 32 < K) {
      const int nb = buf ^ 1;
      gload_lds16(Ap + k0 + 32, &As[nb][tid * 8]);
      gload_lds16(Bp + k0 + 32, &Bs[nb][tid * 8]);
      asm volatile("s_waitcnt vmcnt(2)" ::: "memory");
    } else {
      asm volatile("s_waitcnt vmcnt(0)" ::: "memory");
    }
    __builtin_amdgcn_sched_barrier(0);
    __builtin_amdgcn_s_barrier();
    bf16x8 af[2], bfr[4];
#pragma unroll
    for (int m = 0; m < 2; ++m)
      af[m] = *(const bf16x8*)((const char*)&As[buf][0] + aoff[m]);
#pragma unroll
    for (int n = 0; n < 4; ++n)
      bfr[n] = *(const bf16x8*)((const char*)&Bs[buf][0] + boff[n]);
    __builtin_amdgcn_s_setprio(1);
#pragma unroll
    for (int m = 0; m < 2; ++m)
#pragma unroll
      for (int n = 0; n < 4; ++n)
        acc[m][n] = __builtin_amdgcn_mfma_f32_16x16x32_bf16(af[m], bfr[n], acc[m][n], 0, 0, 0);
    __builtin_amdgcn_s_setprio(0);
    __builtin_amdgcn_s_barrier();
    buf ^= 1;
  }

#pragma unroll
  for (int mm = 0; mm < 2; ++mm) {
#pragma unroll
    for (int nn = 0; nn < 4; ++nn) {
      const int ng = n0 + wn * 64 + nn * 16 + lr;
      if (EPI == 0) {
        const int mat = ng >> 10;
        const int col = ng & 1023;
        const int h = col >> 6, dh = col & 63;
#pragma unroll
        for (int r = 0; r < 4; ++r) {
          const int mg = m0 + wm * 32 + mm * 16 + (hi << 2) + r;
          const int b = mg >> 11, s = mg & 2047;
          if (mat == 0)
            o0[(((size_t)(b * 16 + h)) * 2048 + s) * 64 + dh] = f2bf(acc[mm][nn][r] * QSCALE);
          else if (mat == 1)
            o1[(((size_t)(b * 16 + h)) * 2048 + s) * 64 + dh] = f2bf(acc[mm][nn][r]);
          else
            o2[(((size_t)(b * 16 + h)) * 64 + dh) * 2048 + s] = f2bf(acc[mm][nn][r]);
        }
      } else {
        const float bv = bias[ng];
#pragma unroll
        for (int r = 0; r < 4; ++r) {
          const int mg = m0 + wm * 32 + mm * 16 + (hi << 2) + r;
          fo[(size_t)mg * N + ng] = acc[mm][nn][r] + bv;
        }
      }
    }
  }
}

// Flash attention, causal.  UNIFORM-WORK pairing + XCD clustering.
// Row-sums on the MFMA pipe; lane-local epilogue normalizer.
__global__ __launch_bounds__(256) void flash_attn(
    const u16* __restrict__ Qg, const u16* __restrict__ Kg,
    const u16* __restrict__ Vtg, u16* __restrict__ ctx)
{
  __shared__ __align__(16) u16 Ks[2][4096];
  __shared__ __align__(16) u16 Vts[2][4096];
  __shared__ __align__(16) u16 PT[4][1024];
  const int tid = threadIdx.x, w = tid >> 6, l = tid & 63;
  const int lr = l & 15, hi = l >> 4;
  const int bid = blockIdx.x;
  const int xcd = bid & 7, j = bid >> 3;
  const int bh = xcd + ((j & 3) << 3);
  const int p = j >> 2;              // pair index [0,16)
  const size_t kqbase = (size_t)bh * (2048 * 64);
  const int h = bh & 15, b = bh >> 4;

  // ones B-fragment (bf16 1.0 = 0x3F80)
  bf16x8 onesf;
#pragma unroll
  for (int i = 0; i < 8; ++i) onesf[i] = (short)0x3F80;

  const int c0 = w * 128 + l;
  const int c1 = c0 + 64;
  const int r0 = c0 >> 3, p0 = c0 & 7;
  const int r1 = c1 >> 3, p1 = c1 & 7;
  const u16* kg0 = Kg + kqbase + r0 * 64 + p0 * 8;
  const u16* kg1 = Kg + kqbase + r1 * 64 + p1 * 8;
  const u16* vg0 = Vtg + kqbase + (size_t)r0 * 2048 + p0 * 8;
  const u16* vg1 = Vtg + kqbase + (size_t)r1 * 2048 + p1 * 8;
  const int kw0 = (r0 << 7) + ((p0 ^ (r0 & 7)) << 4);
  const int kw1 = (r1 << 7) + ((p1 ^ (r1 & 7)) << 4);

  for (int seg = 0; seg < 2; ++seg) {
    const int qt = seg ? (31 - p) : p;
    const int q0 = qt * 64;
    const int nkt = qt + 1;
    const int qg = q0 + w * 16 + lr;

    if (seg) __builtin_amdgcn_s_barrier();   // protect LDS reuse across segments

    bf16x8 qf[2];
    {
      const u16* qp = Qg + kqbase + (size_t)(q0 + w * 16 + lr) * 64 + hi * 8;
      qf[0] = *(const bf16x8*)(qp);
      qf[1] = *(const bf16x8*)(qp + 32);
    }

    f32x4 acc[4] = {};
    f32x4 acc_ls = {};

    // prologue: tile 0 -> regs -> buf0; issue tile 1 loads
    bf16x8 sk0 = *(const bf16x8*)kg0;
    bf16x8 sk1 = *(const bf16x8*)kg1;
    bf16x8 sv0 = *(const bf16x8*)vg0;
    bf16x8 sv1 = *(const bf16x8*)vg1;
    *(bf16x8*)((char*)&Ks[0][0] + kw0) = sk0;
    *(bf16x8*)((char*)&Ks[0][0] + kw1) = sk1;
    *(bf16x8*)((char*)&Vts[0][0] + kw0) = sv0;
    *(bf16x8*)((char*)&Vts[0][0] + kw1) = sv1;
    if (nkt > 1) {
      sk0 = *(const bf16x8*)(kg0 + 4096);
      sk1 = *(const bf16x8*)(kg1 + 4096);
      sv0 = *(const bf16x8*)(vg0 + 64);
      sv1 = *(const bf16x8*)(vg1 + 64);
    }
    asm volatile("s_waitcnt lgkmcnt(0)" ::: "memory");
    __builtin_amdgcn_sched_barrier(0);
    __builtin_amdgcn_s_barrier();

    int buf = 0;
    for (int kt = 0; kt < nkt; ++kt) {
      {
        const u16* ksb = &Ks[buf][0];
        const u16* vsb = &Vts[buf][0];
        f32x4 sv[4];
        __builtin_amdgcn_s_setprio(1);
#pragma unroll
        for (int cf = 0; cf < 4; ++cf) {
          f32x4 z = {};
#pragma unroll
          for (int ch = 0; ch < 2; ++ch) {
            const int krow = cf * 16 + lr;
            const int boff = ((krow << 7) + ((ch * 32 + hi * 8) << 1)) ^ ((krow & 7) << 4);
            bf16x8 kf = *(const bf16x8*)((const char*)ksb + boff);
            z = __builtin_amdgcn_mfma_f32_16x16x32_bf16(kf, qf[ch], z, 0, 0, 0);
          }
          sv[cf] = z;
        }
        __builtin_amdgcn_s_setprio(0);

        const bool diag = (kt == nkt - 1);
        const int kb = kt * 64 + hi * 4;
#pragma unroll
        for (int cf = 0; cf < 4; ++cf) {
          f32x4 pv;
#pragma unroll
          for (int r = 0; r < 4; ++r) {
            float s = sv[cf][r];
            if (diag && (kb + cf * 16 + r) > qg) s = -1e30f;
            pv[r] = exp2f(s);
          }
          sv[cf] = pv;
        }

        {
          const int rowb = lr << 7;
          const int swz = (lr & 7) << 4;
#pragma unroll
          for (int cf = 0; cf < 4; ++cf) {
            uint32_t d0 = pk_bf16(sv[cf][0], sv[cf][1]);
            uint32_t d1 = pk_bf16(sv[cf][2], sv[cf][3]);
            uint2 val = { d0, d1 };
            const int boff = (rowb + ((cf * 16 + hi * 4) << 1)) ^ swz;
            *(uint2*)((char*)&PT[w][0] + boff) = val;
          }
        }

#pragma unroll
        for (int ch = 0; ch < 2; ++ch) {
          const int boffp = ((lr << 7) + (ch * 64 + hi * 16)) ^ ((lr & 7) << 4);
          bf16x8 pa = *(const bf16x8*)((const char*)&PT[w][0] + boffp);
          __builtin_amdgcn_s_setprio(1);
          acc_ls = __builtin_amdgcn_mfma_f32_16x16x32_bf16(pa, onesf, acc_ls, 0, 0, 0);
#pragma unroll
          for (int df = 0; df < 4; ++df) {
            const int vrow = df * 16 + lr;
            const int boffv = ((vrow << 7) + ((ch * 32 + hi * 8) << 1)) ^ ((vrow & 7) << 4);
            bf16x8 vf = *(const bf16x8*)((const char*)vsb + boffv);
            acc[df] = __builtin_amdgcn_mfma_f32_16x16x32_bf16(pa, vf, acc[df], 0, 0, 0);
          }
          __builtin_amdgcn_s_setprio(0);
        }
      }
      if (kt + 1 < nkt) {
        char* kb_ = (char*)&Ks[buf ^ 1][0];
        char* vb_ = (char*)&Vts[buf ^ 1][0];
        *(bf16x8*)(kb_ + kw0) = sk0;
        *(bf16x8*)(kb_ + kw1) = sk1;
        *(bf16x8*)(vb_ + kw0) = sv0;
        *(bf16x8*)(vb_ + kw1) = sv1;
        if (kt + 2 < nkt) {
          sk0 = *(const bf16x8*)(kg0 + (size_t)(kt + 2) * 4096);
          sk1 = *(const bf16x8*)(kg1 + (size_t)(kt + 2) * 4096);
          sv0 = *(const bf16x8*)(vg0 + (kt + 2) * 64);
          sv1 = *(const bf16x8*)(vg1 + (kt + 2) * 64);
        }
        asm volatile("s_waitcnt lgkmcnt(0)" ::: "memory");
        __builtin_amdgcn_sched_barrier(0);
        __builtin_amdgcn_s_barrier();
      }
      buf ^= 1;
    }

    // epilogue: acc_ls[r] is the full row sum for q-row hi*4+r (lane-local)
#pragma unroll
    for (int r = 0; r < 4; ++r) {
      const float inv = 1.0f / acc_ls[r];
      const int s = q0 + w * 16 + hi * 4 + r;
      const size_t rowbase = ((size_t)(b * 2048 + s)) * 1024 + h * 64;
#pragma unroll
      for (int df = 0; df < 4; ++df)
        ctx[rowbase + df * 16 + lr] = f2bf(acc[df][r] * inv);
    }
  }
}

extern "C" void kernel_launch(void* const* d_in, const int* in_sizes, int n_in,
                              void* d_out, int out_size, void* d_ws, size_t ws_size,
                              hipStream_t stream) {
  const float* x  = (const float*)d_in[0];
  const float* Wq = (const float*)d_in[1];
  const float* Wk = (const float*)d_in[2];
  const float* Wv = (const float*)d_in[3];
  const float* Wo = (const float*)d_in[4];
  const float* bo = (const float*)d_in[5];
  float* out = (float*)d_out;

  const size_t MB = 1ull << 20;
  if (ws_size < 48 * MB) return;  // loud failure instead of corruption
  char* ws = (char*)d_ws;
  u16* xb   = (u16*)(ws);             // [4096][1024]
  u16* Wcat = (u16*)(ws + 8 * MB);    // [3072][1024]  (Wq|Wk|Wv)
  u16* Wob  = (u16*)(ws + 14 * MB);   // [1024][1024]
  u16* Qb   = (u16*)(ws + 16 * MB);   // [B,H,S,DH]  (pre-scaled)
  u16* Kb   = (u16*)(ws + 24 * MB);   // [B,H,S,DH]
  u16* Vtb  = (u16*)(ws + 32 * MB);   // [B,H,DH,S]
  u16* ctxb = (u16*)(ws + 40 * MB);   // [4096][1024]

  hipLaunchKernelGGL(cast_all, dim3(4096), dim3(256), 0, stream,
                     x, Wq, Wk, Wv, Wo, xb, Wcat, Wob);
  hipLaunchKernelGGL((gemm_bt<0>), dim3(24, 32), dim3(512), 0, stream,
                     xb, Wcat, 4096, 3072, 1024, Qb, Kb, Vtb, (float*)nullptr, (const float*)nullptr);
  hipLaunchKernelGGL(flash_attn, dim3(512), dim3(256), 0, stream, Qb, Kb, Vtb, ctxb);
  hipLaunchKernelGGL((gemm_bt<1>), dim3(8, 32), dim3(512), 0, stream,
                     ctxb, Wob, 4096, 1024, 1024,
                     (u16*)nullptr, (u16*)nullptr, (u16*)nullptr, out, bo);
}

// Round 32
// 114.529 us; speedup vs baseline: 1.0568x; 1.0255x over previous
//
#include <hip/hip_runtime.h>
#include <stdint.h>

typedef unsigned short u16;
typedef __attribute__((ext_vector_type(8))) short bf16x8;
typedef __attribute__((ext_vector_type(4))) float f32x4;
typedef __attribute__((ext_vector_type(4))) unsigned short u16x4;

__device__ __forceinline__ u16 f2bf(float f) {
  union { float f; uint32_t u; } c; c.f = f;
  uint32_t u = c.u;
  return (u16)((u + 0x7fffu + ((u >> 16) & 1u)) >> 16);
}

__device__ __forceinline__ uint32_t pk_bf16(float lo, float hi) {
  uint32_t d;
  asm("v_cvt_pk_bf16_f32 %0, %1, %2" : "=v"(d) : "v"(lo), "v"(hi));
  return d;
}

__device__ __forceinline__ void gload_lds16(const u16* g, u16* l) {
  __builtin_amdgcn_global_load_lds(
      (const __attribute__((address_space(1))) void*)g,
      (__attribute__((address_space(3))) void*)l, 16, 0, 0);
}

// one launch: x -> xb, Wq|Wk|Wv -> Wcat, Wo -> Wob
__global__ void cast_all(const float* __restrict__ x,
                         const float* __restrict__ Wq, const float* __restrict__ Wk,
                         const float* __restrict__ Wv, const float* __restrict__ Wo,
                         u16* __restrict__ xb, u16* __restrict__ Wcat, u16* __restrict__ Wob) {
  int i = (blockIdx.x * blockDim.x + threadIdx.x) * 4;
  const int stride = gridDim.x * blockDim.x * 4;
  for (; i < 8388608; i += stride) {
    const float* src;
    u16* dst;
    if (i < 4194304) {
      src = x + i; dst = xb + i;
    } else {
      const int j = i - 4194304;
      const int sel = j >> 20, off = j & 1048575;
      src = ((sel == 0) ? Wq : (sel == 1) ? Wk : (sel == 2) ? Wv : Wo) + off;
      dst = (sel < 3) ? (Wcat + j) : (Wob + off);
    }
    float4 v = *reinterpret_cast<const float4*>(src);
    u16x4 o = { f2bf(v.x), f2bf(v.y), f2bf(v.z), f2bf(v.w) };
    *reinterpret_cast<u16x4*>(dst) = o;
  }
}

#define QSCALE 0.18033688011112042f  /* 1/sqrt(64) * log2(e) */

// QKV GEMM: C = A @ B^T.  128x128 tile, BK=32, 512 threads = 8 waves
// (4M x 2N).  global_load_lds staging (1 A + 1 B chunk/thread, counted
// vmcnt(2)); slot-swizzle.  R26/R29-measured best: 45.9 us.
// Epilogue: scatter Q(pre-scaled)/K/Vt.
__global__ __launch_bounds__(512) void gemm_qkv(
    const u16* __restrict__ A, const u16* __restrict__ B,
    u16* __restrict__ o0, u16* __restrict__ o1, u16* __restrict__ o2)
{
  const int K = 1024;
  __shared__ __align__(16) u16 As[2][128 * 32];
  __shared__ __align__(16) u16 Bs[2][128 * 32];
  const int tid = threadIdx.x;
  const int w = tid >> 6, l = tid & 63;
  const int m0 = blockIdx.y * 128, n0 = blockIdx.x * 128;
  const int wm = w >> 1, wn = w & 1;
  const int lr = l & 15, hi = l >> 4;
  f32x4 acc[2][4] = {};

  const int ra = tid >> 2, sa = (tid & 3) ^ ((ra >> 1) & 3);
  const u16* Ap = A + (size_t)(m0 + ra) * K + sa * 8;
  const u16* Bp = B + (size_t)(n0 + ra) * K + sa * 8;

  gload_lds16(Ap, &As[0][tid * 8]);
  gload_lds16(Bp, &Bs[0][tid * 8]);

  int aoff[2], boff[4];
#pragma unroll
  for (int m = 0; m < 2; ++m) {
    const int row = wm * 32 + m * 16 + lr;
    aoff[m] = row * 64 + ((hi ^ ((row >> 1) & 3)) << 4);
  }
#pragma unroll
  for (int n = 0; n < 4; ++n) {
    const int row = wn * 64 + n * 16 + lr;
    boff[n] = row * 64 + ((hi ^ ((row >> 1) & 3)) << 4);
  }

  int buf = 0;
  for (int k0 = 0; k0 < K; k0 += 32) {
    if (k0 + 32 < K) {
      const int nb = buf ^ 1;
      gload_lds16(Ap + k0 + 32, &As[nb][tid * 8]);
      gload_lds16(Bp + k0 + 32, &Bs[nb][tid * 8]);
      asm volatile("s_waitcnt vmcnt(2)" ::: "memory");
    } else {
      asm volatile("s_waitcnt vmcnt(0)" ::: "memory");
    }
    __builtin_amdgcn_sched_barrier(0);
    __builtin_amdgcn_s_barrier();
    bf16x8 af[2], bfr[4];
#pragma unroll
    for (int m = 0; m < 2; ++m)
      af[m] = *(const bf16x8*)((const char*)&As[buf][0] + aoff[m]);
#pragma unroll
    for (int n = 0; n < 4; ++n)
      bfr[n] = *(const bf16x8*)((const char*)&Bs[buf][0] + boff[n]);
    __builtin_amdgcn_s_setprio(1);
#pragma unroll
    for (int m = 0; m < 2; ++m)
#pragma unroll
      for (int n = 0; n < 4; ++n)
        acc[m][n] = __builtin_amdgcn_mfma_f32_16x16x32_bf16(af[m], bfr[n], acc[m][n], 0, 0, 0);
    __builtin_amdgcn_s_setprio(0);
    __builtin_amdgcn_s_barrier();
    buf ^= 1;
  }

#pragma unroll
  for (int mm = 0; mm < 2; ++mm) {
#pragma unroll
    for (int nn = 0; nn < 4; ++nn) {
      const int ng = n0 + wn * 64 + nn * 16 + lr;
      const int mat = ng >> 10;
      const int col = ng & 1023;
      const int h = col >> 6, dh = col & 63;
#pragma unroll
      for (int r = 0; r < 4; ++r) {
        const int mg = m0 + wm * 32 + mm * 16 + (hi << 2) + r;
        const int b = mg >> 11, s = mg & 2047;
        if (mat == 0)
          o0[(((size_t)(b * 16 + h)) * 2048 + s) * 64 + dh] = f2bf(acc[mm][nn][r] * QSCALE);
        else if (mat == 1)
          o1[(((size_t)(b * 16 + h)) * 2048 + s) * 64 + dh] = f2bf(acc[mm][nn][r]);
        else
          o2[(((size_t)(b * 16 + h)) * 64 + dh) * 2048 + s] = f2bf(acc[mm][nn][r]);
      }
    }
  }
}

// Out-projection GEMM: C = ctx @ Wo^T + bias, fp32 out.  64x128 tile
// (R25-verified kernel), 256 threads = 4 waves; grid (8,64) = 512 blocks
// = 2 blocks/CU (vs 1 at 128^2) — gemm2 is the 1-blk/CU underfilled case
// where the split measured ~7.4 us in R25's budget.
__global__ __launch_bounds__(256) void gemm_out64(
    const u16* __restrict__ A, const u16* __restrict__ B,
    float* __restrict__ fo, const float* __restrict__ bias)
{
  const int K = 1024, N = 1024;
  __shared__ __align__(16) u16 As[2][64 * 32];
  __shared__ __align__(16) u16 Bs[2][128 * 32];
  const int tid = threadIdx.x;
  const int w = tid >> 6, l = tid & 63;
  const int m0 = blockIdx.y * 64, n0 = blockIdx.x * 128;
  const int wr = (w >> 1) << 5, wc = (w & 1) << 6;
  const int lr = l & 15, hi = l >> 4;
  f32x4 acc[2][4] = {};

  // staging: A chunk c0=tid (64x32 tile, 256 chunks); B chunks tid, tid+256
  const int ra = tid >> 2, sa = (tid & 3) ^ ((ra >> 1) & 3);
  const int rb1 = (tid + 256) >> 2, sb1 = (tid & 3) ^ ((rb1 >> 1) & 3);
  const u16* Ap = A + (size_t)(m0 + ra) * K + sa * 8;
  const u16* Bp0 = B + (size_t)(n0 + ra) * K + sa * 8;
  const u16* Bp1 = B + (size_t)(n0 + rb1) * K + sb1 * 8;

  gload_lds16(Ap, &As[0][tid * 8]);
  gload_lds16(Bp0, &Bs[0][tid * 8]);
  gload_lds16(Bp1, &Bs[0][(tid + 256) * 8]);

  int aoff[2], boff[4];
#pragma unroll
  for (int m = 0; m < 2; ++m) {
    const int row = wr + m * 16 + lr;
    aoff[m] = row * 64 + ((hi ^ ((row >> 1) & 3)) << 4);
  }
#pragma unroll
  for (int n = 0; n < 4; ++n) {
    const int row = wc + n * 16 + lr;
    boff[n] = row * 64 + ((hi ^ ((row >> 1) & 3)) << 4);
  }

  int buf = 0;
  for (int k0 = 0; k0 < K; k0 += 32) {
    if (k0 + 32 < K) {
      const int nb = buf ^ 1;
      gload_lds16(Ap + k0 + 32, &As[nb][tid * 8]);
      gload_lds16(Bp0 + k0 + 32, &Bs[nb][tid * 8]);
      gload_lds16(Bp1 + k0 + 32, &Bs[nb][(tid + 256) * 8]);
      asm volatile("s_waitcnt vmcnt(3)" ::: "memory");
    } else {
      asm volatile("s_waitcnt vmcnt(0)" ::: "memory");
    }
    __builtin_amdgcn_sched_barrier(0);
    __builtin_amdgcn_s_barrier();
    bf16x8 af[2], bfr[4];
#pragma unroll
    for (int m = 0; m < 2; ++m)
      af[m] = *(const bf16x8*)((const char*)&As[buf][0] + aoff[m]);
#pragma unroll
    for (int n = 0; n < 4; ++n)
      bfr[n] = *(const bf16x8*)((const char*)&Bs[buf][0] + boff[n]);
    __builtin_amdgcn_s_setprio(1);
#pragma unroll
    for (int m = 0; m < 2; ++m)
#pragma unroll
      for (int n = 0; n < 4; ++n)
        acc[m][n] = __builtin_amdgcn_mfma_f32_16x16x32_bf16(af[m], bfr[n], acc[m][n], 0, 0, 0);
    __builtin_amdgcn_s_setprio(0);
    __builtin_amdgcn_s_barrier();
    buf ^= 1;
  }

#pragma unroll
  for (int mm = 0; mm < 2; ++mm) {
#pragma unroll
    for (int nn = 0; nn < 4; ++nn) {
      const int ng = n0 + wc + nn * 16 + lr;
      const float bv = bias[ng];
#pragma unroll
      for (int r = 0; r < 4; ++r) {
        const int mg = m0 + wr + mm * 16 + (hi << 2) + r;
        fo[(size_t)mg * N + ng] = acc[mm][nn][r] + bv;
      }
    }
  }
}

// Flash attention, causal.  UNIFORM-WORK pairing + XCD clustering.
// Row-sums on the MFMA pipe; lane-local epilogue normalizer.
__global__ __launch_bounds__(256) void flash_attn(
    const u16* __restrict__ Qg, const u16* __restrict__ Kg,
    const u16* __restrict__ Vtg, u16* __restrict__ ctx)
{
  __shared__ __align__(16) u16 Ks[2][4096];
  __shared__ __align__(16) u16 Vts[2][4096];
  __shared__ __align__(16) u16 PT[4][1024];
  const int tid = threadIdx.x, w = tid >> 6, l = tid & 63;
  const int lr = l & 15, hi = l >> 4;
  const int bid = blockIdx.x;
  const int xcd = bid & 7, j = bid >> 3;
  const int bh = xcd + ((j & 3) << 3);
  const int p = j >> 2;              // pair index [0,16)
  const size_t kqbase = (size_t)bh * (2048 * 64);
  const int h = bh & 15, b = bh >> 4;

  bf16x8 onesf;
#pragma unroll
  for (int i = 0; i < 8; ++i) onesf[i] = (short)0x3F80;

  const int c0 = w * 128 + l;
  const int c1 = c0 + 64;
  const int r0 = c0 >> 3, p0 = c0 & 7;
  const int r1 = c1 >> 3, p1 = c1 & 7;
  const u16* kg0 = Kg + kqbase + r0 * 64 + p0 * 8;
  const u16* kg1 = Kg + kqbase + r1 * 64 + p1 * 8;
  const u16* vg0 = Vtg + kqbase + (size_t)r0 * 2048 + p0 * 8;
  const u16* vg1 = Vtg + kqbase + (size_t)r1 * 2048 + p1 * 8;
  const int kw0 = (r0 << 7) + ((p0 ^ (r0 & 7)) << 4);
  const int kw1 = (r1 << 7) + ((p1 ^ (r1 & 7)) << 4);

  for (int seg = 0; seg < 2; ++seg) {
    const int qt = seg ? (31 - p) : p;
    const int q0 = qt * 64;
    const int nkt = qt + 1;
    const int qg = q0 + w * 16 + lr;

    if (seg) __builtin_amdgcn_s_barrier();

    bf16x8 qf[2];
    {
      const u16* qp = Qg + kqbase + (size_t)(q0 + w * 16 + lr) * 64 + hi * 8;
      qf[0] = *(const bf16x8*)(qp);
      qf[1] = *(const bf16x8*)(qp + 32);
    }

    f32x4 acc[4] = {};
    f32x4 acc_ls = {};

    bf16x8 sk0 = *(const bf16x8*)kg0;
    bf16x8 sk1 = *(const bf16x8*)kg1;
    bf16x8 sv0 = *(const bf16x8*)vg0;
    bf16x8 sv1 = *(const bf16x8*)vg1;
    *(bf16x8*)((char*)&Ks[0][0] + kw0) = sk0;
    *(bf16x8*)((char*)&Ks[0][0] + kw1) = sk1;
    *(bf16x8*)((char*)&Vts[0][0] + kw0) = sv0;
    *(bf16x8*)((char*)&Vts[0][0] + kw1) = sv1;
    if (nkt > 1) {
      sk0 = *(const bf16x8*)(kg0 + 4096);
      sk1 = *(const bf16x8*)(kg1 + 4096);
      sv0 = *(const bf16x8*)(vg0 + 64);
      sv1 = *(const bf16x8*)(vg1 + 64);
    }
    asm volatile("s_waitcnt lgkmcnt(0)" ::: "memory");
    __builtin_amdgcn_sched_barrier(0);
    __builtin_amdgcn_s_barrier();

    int buf = 0;
    for (int kt = 0; kt < nkt; ++kt) {
      {
        const u16* ksb = &Ks[buf][0];
        const u16* vsb = &Vts[buf][0];
        f32x4 sv[4];
        __builtin_amdgcn_s_setprio(1);
#pragma unroll
        for (int cf = 0; cf < 4; ++cf) {
          f32x4 z = {};
#pragma unroll
          for (int ch = 0; ch < 2; ++ch) {
            const int krow = cf * 16 + lr;
            const int boff = ((krow << 7) + ((ch * 32 + hi * 8) << 1)) ^ ((krow & 7) << 4);
            bf16x8 kf = *(const bf16x8*)((const char*)ksb + boff);
            z = __builtin_amdgcn_mfma_f32_16x16x32_bf16(kf, qf[ch], z, 0, 0, 0);
          }
          sv[cf] = z;
        }
        __builtin_amdgcn_s_setprio(0);

        const bool diag = (kt == nkt - 1);
        const int kb = kt * 64 + hi * 4;
#pragma unroll
        for (int cf = 0; cf < 4; ++cf) {
          f32x4 pv;
#pragma unroll
          for (int r = 0; r < 4; ++r) {
            float s = sv[cf][r];
            if (diag && (kb + cf * 16 + r) > qg) s = -1e30f;
            pv[r] = exp2f(s);
          }
          sv[cf] = pv;
        }

        {
          const int rowb = lr << 7;
          const int swz = (lr & 7) << 4;
#pragma unroll
          for (int cf = 0; cf < 4; ++cf) {
            uint32_t d0 = pk_bf16(sv[cf][0], sv[cf][1]);
            uint32_t d1 = pk_bf16(sv[cf][2], sv[cf][3]);
            uint2 val = { d0, d1 };
            const int boff = (rowb + ((cf * 16 + hi * 4) << 1)) ^ swz;
            *(uint2*)((char*)&PT[w][0] + boff) = val;
          }
        }

#pragma unroll
        for (int ch = 0; ch < 2; ++ch) {
          const int boffp = ((lr << 7) + (ch * 64 + hi * 16)) ^ ((lr & 7) << 4);
          bf16x8 pa = *(const bf16x8*)((const char*)&PT[w][0] + boffp);
          __builtin_amdgcn_s_setprio(1);
          acc_ls = __builtin_amdgcn_mfma_f32_16x16x32_bf16(pa, onesf, acc_ls, 0, 0, 0);
#pragma unroll
          for (int df = 0; df < 4; ++df) {
            const int vrow = df * 16 + lr;
            const int boffv = ((vrow << 7) + ((ch * 32 + hi * 8) << 1)) ^ ((vrow & 7) << 4);
            bf16x8 vf = *(const bf16x8*)((const char*)vsb + boffv);
            acc[df] = __builtin_amdgcn_mfma_f32_16x16x32_bf16(pa, vf, acc[df], 0, 0, 0);
          }
          __builtin_amdgcn_s_setprio(0);
        }
      }
      if (kt + 1 < nkt) {
        char* kb_ = (char*)&Ks[buf ^ 1][0];
        char* vb_ = (char*)&Vts[buf ^ 1][0];
        *(bf16x8*)(kb_ + kw0) = sk0;
        *(bf16x8*)(kb_ + kw1) = sk1;
        *(bf16x8*)(vb_ + kw0) = sv0;
        *(bf16x8*)(vb_ + kw1) = sv1;
        if (kt + 2 < nkt) {
          sk0 = *(const bf16x8*)(kg0 + (size_t)(kt + 2) * 4096);
          sk1 = *(const bf16x8*)(kg1 + (size_t)(kt + 2) * 4096);
          sv0 = *(const bf16x8*)(vg0 + (kt + 2) * 64);
          sv1 = *(const bf16x8*)(vg1 + (kt + 2) * 64);
        }
        asm volatile("s_waitcnt lgkmcnt(0)" ::: "memory");
        __builtin_amdgcn_sched_barrier(0);
        __builtin_amdgcn_s_barrier();
      }
      buf ^= 1;
    }

#pragma unroll
    for (int r = 0; r < 4; ++r) {
      const float inv = 1.0f / acc_ls[r];
      const int s = q0 + w * 16 + hi * 4 + r;
      const size_t rowbase = ((size_t)(b * 2048 + s)) * 1024 + h * 64;
#pragma unroll
      for (int df = 0; df < 4; ++df)
        ctx[rowbase + df * 16 + lr] = f2bf(acc[df][r] * inv);
    }
  }
}

extern "C" void kernel_launch(void* const* d_in, const int* in_sizes, int n_in,
                              void* d_out, int out_size, void* d_ws, size_t ws_size,
                              hipStream_t stream) {
  const float* x  = (const float*)d_in[0];
  const float* Wq = (const float*)d_in[1];
  const float* Wk = (const float*)d_in[2];
  const float* Wv = (const float*)d_in[3];
  const float* Wo = (const float*)d_in[4];
  const float* bo = (const float*)d_in[5];
  float* out = (float*)d_out;

  const size_t MB = 1ull << 20;
  if (ws_size < 48 * MB) return;  // loud failure instead of corruption
  char* ws = (char*)d_ws;
  u16* xb   = (u16*)(ws);             // [4096][1024]
  u16* Wcat = (u16*)(ws + 8 * MB);    // [3072][1024]  (Wq|Wk|Wv)
  u16* Wob  = (u16*)(ws + 14 * MB);   // [1024][1024]
  u16* Qb   = (u16*)(ws + 16 * MB);   // [B,H,S,DH]  (pre-scaled)
  u16* Kb   = (u16*)(ws + 24 * MB);   // [B,H,S,DH]
  u16* Vtb  = (u16*)(ws + 32 * MB);   // [B,H,DH,S]
  u16* ctxb = (u16*)(ws + 40 * MB);   // [4096][1024]

  hipLaunchKernelGGL(cast_all, dim3(4096), dim3(256), 0, stream,
                     x, Wq, Wk, Wv, Wo, xb, Wcat, Wob);
  hipLaunchKernelGGL(gemm_qkv, dim3(24, 32), dim3(512), 0, stream,
                     xb, Wcat, Qb, Kb, Vtb);
  hipLaunchKernelGGL(flash_attn, dim3(512), dim3(256), 0, stream, Qb, Kb, Vtb, ctxb);
  hipLaunchKernelGGL(gemm_out64, dim3(8, 64), dim3(256), 0, stream,
                     ctxb, Wob, out, bo);
}